// Round 10
// baseline (255.870 us; speedup 1.0000x reference)
//
#include <hip/hip_runtime.h>
#include <hip/hip_bf16.h>

#define N_NODES 100000
#define N_EDGES 1600000
#define IN_DIM 128
#define HID 32
#define BW 128                                   // bucket width (dst nodes)
#define NBUCK ((N_NODES + BW - 1) / BW)          // 782
#define CAP 4096                                 // fixed region per bucket (max cnt ~2300)

// Packed edge: (src << 7) | local_dst.  src < 2^17, local_dst < 128.

using bf16x8 = __attribute__((ext_vector_type(8))) short;
using f32x4  = __attribute__((ext_vector_type(4))) float;

__device__ __forceinline__ short f2bf(float f) {
    return __builtin_bit_cast(short, __float2bfloat16(f));
}
__device__ __forceinline__ float bf2f(short s) {
    return __bfloat162float(__builtin_bit_cast(__hip_bfloat16, s));
}

// ======================= Layer-1 GEMM (MFMA, hi/lo bf16 = f32 accuracy) ===============
// h1(bf16) = x@W1; el1/er1 from f32 accumulators. Inits gcur[b] = b*CAP.
__global__ __launch_bounds__(256) void gemm1_kernel(
    const float* __restrict__ x, const float* __restrict__ W,
    const float* __restrict__ al, const float* __restrict__ ar,
    __hip_bfloat16* __restrict__ h, float* __restrict__ el, float* __restrict__ er,
    int* __restrict__ gcur)
{
    __shared__ float Xs[64][132];    // 64 rows x 128 (+4 pad) = 33 KB
    const int tid = threadIdx.x;
    const int row0 = blockIdx.x * 64;

    const int gid = blockIdx.x * 256 + tid;
    if (gid < NBUCK) gcur[gid] = gid * CAP;      // cursor init (no bhist/bscan needed)

    const int lane = tid & 63, wid = tid >> 6;
    const int l15 = lane & 15, g = lane >> 4;

    // B fragments: W hi/lo, 4 k-chunks x 2 col-tiles. Slot (g,j) <- k = 32q+8g+j.
    bf16x8 bh[4][2], bl[4][2];
    #pragma unroll
    for (int q = 0; q < 4; ++q)
        #pragma unroll
        for (int ct = 0; ct < 2; ++ct)
            #pragma unroll
            for (int j = 0; j < 8; ++j) {
                const float wv = W[(32 * q + 8 * g + j) * HID + ct * 16 + l15];
                const short hi = f2bf(wv);
                bh[q][ct][j] = hi;
                bl[q][ct][j] = f2bf(wv - bf2f(hi));
            }

    // Stage 64 rows of x (coalesced float4)
    #pragma unroll
    for (int i = 0; i < 8; ++i) {
        const int f = tid + 256 * i;
        const int r = f >> 5, c4 = f & 31;
        const int gr = row0 + r;
        float4 v = make_float4(0.f, 0.f, 0.f, 0.f);
        if (gr < N_NODES) v = ((const float4*)x)[(size_t)gr * 32 + c4];
        *(float4*)&Xs[r][c4 * 4] = v;
    }
    __syncthreads();

    const int tile = blockIdx.x * 4 + wid;       // 16-row tile id
    if (tile * 16 >= N_NODES) return;
    const int rl = wid * 16 + l15;               // local row for A fragment

    f32x4 acc0 = {0.f, 0.f, 0.f, 0.f}, acc1 = {0.f, 0.f, 0.f, 0.f};
    #pragma unroll
    for (int q = 0; q < 4; ++q) {
        const float4 xa = *(const float4*)&Xs[rl][32 * q + 8 * g];
        const float4 xb = *(const float4*)&Xs[rl][32 * q + 8 * g + 4];
        const float xs[8] = {xa.x, xa.y, xa.z, xa.w, xb.x, xb.y, xb.z, xb.w};
        bf16x8 ah, alo;
        #pragma unroll
        for (int j = 0; j < 8; ++j) {
            const short hi = f2bf(xs[j]);
            ah[j] = hi;
            alo[j] = f2bf(xs[j] - bf2f(hi));
        }
        acc0 = __builtin_amdgcn_mfma_f32_16x16x32_bf16(ah,  bh[q][0], acc0, 0, 0, 0);
        acc0 = __builtin_amdgcn_mfma_f32_16x16x32_bf16(alo, bh[q][0], acc0, 0, 0, 0);
        acc0 = __builtin_amdgcn_mfma_f32_16x16x32_bf16(ah,  bl[q][0], acc0, 0, 0, 0);
        acc1 = __builtin_amdgcn_mfma_f32_16x16x32_bf16(ah,  bh[q][1], acc1, 0, 0, 0);
        acc1 = __builtin_amdgcn_mfma_f32_16x16x32_bf16(alo, bh[q][1], acc1, 0, 0, 0);
        acc1 = __builtin_amdgcn_mfma_f32_16x16x32_bf16(ah,  bl[q][1], acc1, 0, 0, 0);
    }

    // Epilogue. D layout (verified): col = lane&15, row = (lane>>4)*4 + reg.
    const int grow0 = tile * 16 + 4 * g;
    const float a0 = al[l15], a1 = al[16 + l15];
    const float r0 = ar[l15], r1 = ar[16 + l15];
    float pel[4], per_[4];
    #pragma unroll
    for (int i = 0; i < 4; ++i) {
        const int grow = grow0 + i;
        h[(size_t)grow * HID + l15]      = __float2bfloat16(acc0[i]);
        h[(size_t)grow * HID + 16 + l15] = __float2bfloat16(acc1[i]);
        pel[i]  = acc0[i] * a0 + acc1[i] * a1;
        per_[i] = acc0[i] * r0 + acc1[i] * r1;
    }
    #pragma unroll
    for (int m = 1; m < 16; m <<= 1)
        #pragma unroll
        for (int i = 0; i < 4; ++i) {
            pel[i]  += __shfl_xor(pel[i],  m, 16);
            per_[i] += __shfl_xor(per_[i], m, 16);
        }
    if (l15 == 0)
        #pragma unroll
        for (int i = 0; i < 4; ++i) { el[grow0 + i] = pel[i]; er[grow0 + i] = per_[i]; }
}

// ======================= Binning (block-aggregated multisplit, fixed regions) =========
// 512 threads x 16 edges = 8192 edges/block: per-(block,bucket) runs average ~10 slots,
// doubling HBM line fill on the scattered pair writes vs the 4096-edge version.
__global__ __launch_bounds__(512) void bin_kernel(const int* __restrict__ src,
                                                  const int* __restrict__ dst,
                                                  int* __restrict__ gcur,
                                                  int* __restrict__ pairs)
{
    __shared__ int hist[NBUCK];
    __shared__ int cur[NBUCK];
    const int tid = threadIdx.x;
    for (int i = tid; i < NBUCK; i += 512) hist[i] = 0;
    __syncthreads();

    const int t = blockIdx.x * 512 + tid;         // 16-edge group id
    const bool act = t < N_EDGES / 16;
    int4 sv[4], dv[4];
    if (act) {
        const int4* s4 = (const int4*)src + (size_t)t * 4;
        const int4* d4 = (const int4*)dst + (size_t)t * 4;
        #pragma unroll
        for (int q = 0; q < 4; ++q) { sv[q] = s4[q]; dv[q] = d4[q]; }
        #pragma unroll
        for (int q = 0; q < 4; ++q) {
            atomicAdd(&hist[dv[q].x >> 7], 1); atomicAdd(&hist[dv[q].y >> 7], 1);
            atomicAdd(&hist[dv[q].z >> 7], 1); atomicAdd(&hist[dv[q].w >> 7], 1);
        }
    }
    __syncthreads();
    for (int i = tid; i < NBUCK; i += 512) {
        const int hv = hist[i];
        cur[i] = hv ? atomicAdd(&gcur[i], hv) : 0;
    }
    __syncthreads();
    if (act) {
        #pragma unroll
        for (int q = 0; q < 4; ++q) {
            const int ss[4] = {sv[q].x, sv[q].y, sv[q].z, sv[q].w};
            const int dd[4] = {dv[q].x, dv[q].y, dv[q].z, dv[q].w};
            #pragma unroll
            for (int r = 0; r < 4; ++r) {
                const int slot = atomicAdd(&cur[dd[r] >> 7], 1);
                pairs[slot] = (ss[r] << 7) | (dd[r] & (BW - 1));
            }
        }
    }
}

// ======================= Bucket-local sort (in LDS) + fused layer-1 weights ===========
// One block per bucket: stage region in LDS, hist+scan+scatter there, write sorted
// order back in place (coalesced) while computing w1 = exp(leakyrelu(el[src]+er[dst])).
__global__ __launch_bounds__(256) void lsort_kernel(
    const int* __restrict__ gcur, int* __restrict__ pairs,
    const float* __restrict__ el, const float* __restrict__ er,
    int* __restrict__ deg, int* __restrict__ rowptr, float* __restrict__ w1)
{
    __shared__ int lp[CAP];     // 16 KB
    __shared__ int lc[CAP];     // 16 KB
    __shared__ int lhist[BW];
    __shared__ int lcur[BW];
    __shared__ float ers[BW];
    __shared__ int w0tot;
    const int tid = threadIdx.x;
    const int b = blockIdx.x;
    const int rbase = b * CAP;
    const int node0 = b * BW;
    int ecnt = gcur[b] - rbase;
    if (ecnt > CAP) ecnt = CAP;                  // safety clamp (never expected)
    if (tid < BW) {
        lhist[tid] = 0;
        ers[tid] = (node0 + tid < N_NODES) ? er[node0 + tid] : 0.f;
    }
    __syncthreads();
    for (int i = tid; i < ecnt; i += 256) {
        const int p = pairs[rbase + i];
        lp[i] = p;
        atomicAdd(&lhist[p & (BW - 1)], 1);
    }
    __syncthreads();
    // exclusive scan of 128 local degrees (2 waves)
    const int lane = tid & 63;
    int v = 0;
    if (tid < BW) v = lhist[tid];
    int pre = v;
    #pragma unroll
    for (int off = 1; off < 64; off <<= 1) {
        const int n = __shfl_up(pre, off, 64);
        if (lane >= off) pre += n;
    }
    if (tid == 63) w0tot = pre;
    __syncthreads();
    if (tid < BW) {
        const int ex = pre - v + (tid >= 64 ? w0tot : 0);
        lcur[tid] = ex;
        const int node = node0 + tid;
        if (node < N_NODES) { deg[node] = v; rowptr[node] = rbase + ex; }
    }
    __syncthreads();
    for (int i = tid; i < ecnt; i += 256) {
        const int p = lp[i];
        const int slot = atomicAdd(&lcur[p & (BW - 1)], 1);
        lc[slot] = p;
    }
    __syncthreads();
    for (int i = tid; i < ecnt; i += 256) {
        const int p = lc[i];
        pairs[rbase + i] = p;
        float sc = el[p >> 7] + ers[p & (BW - 1)];
        sc = sc > 0.f ? sc : 0.2f * sc;              // LeakyReLU(0.2)
        w1[rbase + i] = __expf(sc);
    }
}

// ======================= Layer-2 weights ==============================================
// Streaming over each bucket's sorted range: w2 = exp(leakyrelu(el2[src]+er2[dst])).
__global__ __launch_bounds__(256) void wcalc_kernel(
    const int* __restrict__ gcur, const int* __restrict__ csr,
    const float* __restrict__ el, const float* __restrict__ er,
    float* __restrict__ w)
{
    __shared__ float ers[BW];
    const int tid = threadIdx.x;
    const int b = blockIdx.x;
    const int rbase = b * CAP;
    const int node0 = b * BW;
    if (tid < BW) ers[tid] = (node0 + tid < N_NODES) ? er[node0 + tid] : 0.f;
    __syncthreads();
    int ecnt = gcur[b] - rbase;
    if (ecnt > CAP) ecnt = CAP;
    for (int i = tid; i < ecnt; i += 256) {
        const int p = csr[rbase + i];
        float sc = el[p >> 7] + ers[p & (BW - 1)];
        sc = sc > 0.f ? sc : 0.2f * sc;
        w[rbase + i] = __expf(sc);
    }
}

// ======================= Gather-aggregate (precomputed w; fused next-layer GEMM) ======
// One node per 32-lane group. csr/w are broadcast sequential streams; h is the single
// per-lane random stream (bf16, 64B/row). 8-deep unroll = 8 independent h loads in
// flight. den is identical in all lanes (broadcast w) -> no reduction.
// MODE 0 epilogue: x2 = elu(num/den + b1); h2 = x2@W2 (shfl outer product vs LDS W2);
//                  el2/er2 by shuffle reduction.   MODE 1: out = num/den + b2.
template <int MODE>
__global__ __launch_bounds__(256) void gather_kernel(
    const int* __restrict__ rowptr, const int* __restrict__ deg,
    const int* __restrict__ csr, const float* __restrict__ w,
    const __hip_bfloat16* __restrict__ h, const float* __restrict__ bias,
    const float* __restrict__ W2, const float* __restrict__ al2,
    const float* __restrict__ ar2,
    __hip_bfloat16* __restrict__ h2, float* __restrict__ el2,
    float* __restrict__ er2, float* __restrict__ out)
{
    const int tid = threadIdx.x;
    float* W2s = nullptr;
    if constexpr (MODE == 0) {
        __shared__ float W2s_[HID * HID];   // 4 KB (allocated only in MODE 0)
        W2s = W2s_;
        ((float4*)W2s)[tid] = ((const float4*)W2)[tid];
        __syncthreads();
    }
    const int node = blockIdx.x * 8 + (tid >> 5);    // grid = N/8 exactly
    const int col = tid & 31;
    const int cnt = deg[node];
    const int start = rowptr[node];
    float acc = 0.f, den = 0.f;
    int j = 0;
    for (; j + 7 < cnt; j += 8) {
        const int p0 = csr[start + j];
        const int p1 = csr[start + j + 1];
        const int p2 = csr[start + j + 2];
        const int p3 = csr[start + j + 3];
        const int p4 = csr[start + j + 4];
        const int p5 = csr[start + j + 5];
        const int p6 = csr[start + j + 6];
        const int p7 = csr[start + j + 7];
        const float w0 = w[start + j];
        const float w1v = w[start + j + 1];
        const float w2v = w[start + j + 2];
        const float w3v = w[start + j + 3];
        const float w4v = w[start + j + 4];
        const float w5v = w[start + j + 5];
        const float w6v = w[start + j + 6];
        const float w7v = w[start + j + 7];
        const float h0 = __bfloat162float(h[(size_t)(p0 >> 7) * HID + col]);
        const float h1 = __bfloat162float(h[(size_t)(p1 >> 7) * HID + col]);
        const float h2v = __bfloat162float(h[(size_t)(p2 >> 7) * HID + col]);
        const float h3 = __bfloat162float(h[(size_t)(p3 >> 7) * HID + col]);
        const float h4 = __bfloat162float(h[(size_t)(p4 >> 7) * HID + col]);
        const float h5 = __bfloat162float(h[(size_t)(p5 >> 7) * HID + col]);
        const float h6 = __bfloat162float(h[(size_t)(p6 >> 7) * HID + col]);
        const float h7 = __bfloat162float(h[(size_t)(p7 >> 7) * HID + col]);
        den += ((w0 + w1v) + (w2v + w3v)) + ((w4v + w5v) + (w6v + w7v));
        acc += (w0 * h0 + w1v * h1 + w2v * h2v + w3v * h3)
             + (w4v * h4 + w5v * h5 + w6v * h6 + w7v * h7);
    }
    for (; j < cnt; ++j) {
        const int p = csr[start + j];
        const float wv = w[start + j];
        den += wv;
        acc += wv * __bfloat162float(h[(size_t)(p >> 7) * HID + col]);
    }

    float v = den > 0.f ? acc / den : 0.f;
    v += bias[col];
    if constexpr (MODE == 0) {
        v = v > 0.f ? v : expm1f(v);                 // ELU -> x2 value in this lane
        float hacc = 0.f;
        #pragma unroll
        for (int k = 0; k < HID; ++k)
            hacc += __shfl(v, k, 32) * W2s[k * HID + col];  // h2 = x2 @ W2
        h2[(size_t)node * HID + col] = __float2bfloat16(hacc);
        float pel = hacc * al2[col], per = hacc * ar2[col];
        #pragma unroll
        for (int mm = 16; mm > 0; mm >>= 1) {
            pel += __shfl_xor(pel, mm, 32);
            per += __shfl_xor(per, mm, 32);
        }
        if (col == 0) { el2[node] = pel; er2[node] = per; }
    } else {
        out[(size_t)node * HID + col] = v;
    }
}

extern "C" void kernel_launch(void* const* d_in, const int* in_sizes, int n_in,
                              void* d_out, int out_size, void* d_ws, size_t ws_size,
                              hipStream_t stream) {
    const float* features = (const float*)d_in[0];
    const int*   src      = (const int*)d_in[1];
    const int*   dst      = (const int*)d_in[2];
    const float* W1       = (const float*)d_in[3];
    const float* al1      = (const float*)d_in[4];
    const float* ar1      = (const float*)d_in[5];
    const float* b1       = (const float*)d_in[6];
    const float* W2       = (const float*)d_in[7];
    const float* al2      = (const float*)d_in[8];
    const float* ar2      = (const float*)d_in[9];
    const float* b2       = (const float*)d_in[10];
    float* out = (float*)d_out;

    // Workspace (~42 MB)
    int*  gcur   = (int*)d_ws;                          // 784
    int*  deg    = gcur + 784;                          // 100k
    int*  rowptr = deg + N_NODES;                       // 100k
    int*  pairs  = rowptr + N_NODES;                    // NBUCK*CAP (12.8 MB), sorted in place
    float* wbuf  = (float*)(pairs + NBUCK * CAP);       // NBUCK*CAP (12.8 MB)
    __hip_bfloat16* h1 = (__hip_bfloat16*)(wbuf + NBUCK * CAP);   // 6.4 MB
    float* el1 = (float*)(h1 + (size_t)N_NODES * HID);
    float* er1 = el1 + N_NODES;
    __hip_bfloat16* h2 = (__hip_bfloat16*)(er1 + N_NODES);        // 6.4 MB
    float* el2 = (float*)(h2 + (size_t)N_NODES * HID);
    float* er2 = el2 + N_NODES;

    const int NB_E16 = (N_EDGES / 16 + 511) / 512;      // 196 (16 edges/thread, 512 thr)
    const int NB_G1  = (N_NODES + 63) / 64;             // 1563

    // Layer-1 GEMM (MFMA) + cursor init
    gemm1_kernel<<<NB_G1, 256, 0, stream>>>(features, W1, al1, ar1,
                                            h1, el1, er1, gcur);
    // Edge binning into fixed bucket regions; in-LDS bucket sort -> node CSR (+ w1)
    bin_kernel<<<NB_E16, 512, 0, stream>>>(src, dst, gcur, pairs);
    lsort_kernel<<<NBUCK, 256, 0, stream>>>(gcur, pairs, el1, er1,
                                            deg, rowptr, wbuf);
    // Layer-1 aggregate + ELU + fused layer-2 GEMM -> h2, el2, er2
    gather_kernel<0><<<N_NODES / 8, 256, 0, stream>>>(rowptr, deg, pairs, wbuf,
                                                      h1, b1, W2, al2, ar2,
                                                      h2, el2, er2, nullptr);
    // Layer-2 weights, then final aggregate -> out = num/den + b2
    wcalc_kernel<<<NBUCK, 256, 0, stream>>>(gcur, pairs, el2, er2, wbuf);
    gather_kernel<1><<<N_NODES / 8, 256, 0, stream>>>(rowptr, deg, pairs, wbuf,
                                                      h2, b2,
                                                      nullptr, nullptr, nullptr,
                                                      nullptr, nullptr, nullptr, out);
}

// Round 11
// 250.198 us; speedup vs baseline: 1.0227x; 1.0227x over previous
//
#include <hip/hip_runtime.h>
#include <hip/hip_bf16.h>

#define N_NODES 100000
#define N_EDGES 1600000
#define IN_DIM 128
#define HID 32
#define BW 128                                   // bucket width (dst nodes)
#define NBUCK ((N_NODES + BW - 1) / BW)          // 782
#define CAP 4096                                 // fixed region per bucket (max cnt ~2300)

// Packed edge: (src << 7) | local_dst.  src < 2^17, local_dst < 128.

using bf16x8 = __attribute__((ext_vector_type(8))) short;
using f32x4  = __attribute__((ext_vector_type(4))) float;

__device__ __forceinline__ short f2bf(float f) {
    return __builtin_bit_cast(short, __float2bfloat16(f));
}
__device__ __forceinline__ float bf2f(short s) {
    return __bfloat162float(__builtin_bit_cast(__hip_bfloat16, s));
}

// ======================= Layer-1 GEMM (MFMA, hi/lo bf16 = f32 accuracy) ===============
// h1(bf16) = x@W1; el1/er1 from f32 accumulators. Inits gcur[b] = b*CAP.
__global__ __launch_bounds__(256) void gemm1_kernel(
    const float* __restrict__ x, const float* __restrict__ W,
    const float* __restrict__ al, const float* __restrict__ ar,
    __hip_bfloat16* __restrict__ h, float* __restrict__ el, float* __restrict__ er,
    int* __restrict__ gcur)
{
    __shared__ float Xs[64][132];    // 64 rows x 128 (+4 pad) = 33 KB
    const int tid = threadIdx.x;
    const int row0 = blockIdx.x * 64;

    const int gid = blockIdx.x * 256 + tid;
    if (gid < NBUCK) gcur[gid] = gid * CAP;      // cursor init (no bhist/bscan needed)

    const int lane = tid & 63, wid = tid >> 6;
    const int l15 = lane & 15, g = lane >> 4;

    // B fragments: W hi/lo, 4 k-chunks x 2 col-tiles. Slot (g,j) <- k = 32q+8g+j.
    bf16x8 bh[4][2], bl[4][2];
    #pragma unroll
    for (int q = 0; q < 4; ++q)
        #pragma unroll
        for (int ct = 0; ct < 2; ++ct)
            #pragma unroll
            for (int j = 0; j < 8; ++j) {
                const float wv = W[(32 * q + 8 * g + j) * HID + ct * 16 + l15];
                const short hi = f2bf(wv);
                bh[q][ct][j] = hi;
                bl[q][ct][j] = f2bf(wv - bf2f(hi));
            }

    // Stage 64 rows of x (coalesced float4)
    #pragma unroll
    for (int i = 0; i < 8; ++i) {
        const int f = tid + 256 * i;
        const int r = f >> 5, c4 = f & 31;
        const int gr = row0 + r;
        float4 v = make_float4(0.f, 0.f, 0.f, 0.f);
        if (gr < N_NODES) v = ((const float4*)x)[(size_t)gr * 32 + c4];
        *(float4*)&Xs[r][c4 * 4] = v;
    }
    __syncthreads();

    const int tile = blockIdx.x * 4 + wid;       // 16-row tile id
    if (tile * 16 >= N_NODES) return;
    const int rl = wid * 16 + l15;               // local row for A fragment

    f32x4 acc0 = {0.f, 0.f, 0.f, 0.f}, acc1 = {0.f, 0.f, 0.f, 0.f};
    #pragma unroll
    for (int q = 0; q < 4; ++q) {
        const float4 xa = *(const float4*)&Xs[rl][32 * q + 8 * g];
        const float4 xb = *(const float4*)&Xs[rl][32 * q + 8 * g + 4];
        const float xs[8] = {xa.x, xa.y, xa.z, xa.w, xb.x, xb.y, xb.z, xb.w};
        bf16x8 ah, alo;
        #pragma unroll
        for (int j = 0; j < 8; ++j) {
            const short hi = f2bf(xs[j]);
            ah[j] = hi;
            alo[j] = f2bf(xs[j] - bf2f(hi));
        }
        acc0 = __builtin_amdgcn_mfma_f32_16x16x32_bf16(ah,  bh[q][0], acc0, 0, 0, 0);
        acc0 = __builtin_amdgcn_mfma_f32_16x16x32_bf16(alo, bh[q][0], acc0, 0, 0, 0);
        acc0 = __builtin_amdgcn_mfma_f32_16x16x32_bf16(ah,  bl[q][0], acc0, 0, 0, 0);
        acc1 = __builtin_amdgcn_mfma_f32_16x16x32_bf16(ah,  bh[q][1], acc1, 0, 0, 0);
        acc1 = __builtin_amdgcn_mfma_f32_16x16x32_bf16(alo, bh[q][1], acc1, 0, 0, 0);
        acc1 = __builtin_amdgcn_mfma_f32_16x16x32_bf16(ah,  bl[q][1], acc1, 0, 0, 0);
    }

    // Epilogue. D layout (verified): col = lane&15, row = (lane>>4)*4 + reg.
    const int grow0 = tile * 16 + 4 * g;
    const float a0 = al[l15], a1 = al[16 + l15];
    const float r0 = ar[l15], r1 = ar[16 + l15];
    float pel[4], per_[4];
    #pragma unroll
    for (int i = 0; i < 4; ++i) {
        const int grow = grow0 + i;
        h[(size_t)grow * HID + l15]      = __float2bfloat16(acc0[i]);
        h[(size_t)grow * HID + 16 + l15] = __float2bfloat16(acc1[i]);
        pel[i]  = acc0[i] * a0 + acc1[i] * a1;
        per_[i] = acc0[i] * r0 + acc1[i] * r1;
    }
    #pragma unroll
    for (int m = 1; m < 16; m <<= 1)
        #pragma unroll
        for (int i = 0; i < 4; ++i) {
            pel[i]  += __shfl_xor(pel[i],  m, 16);
            per_[i] += __shfl_xor(per_[i], m, 16);
        }
    if (l15 == 0)
        #pragma unroll
        for (int i = 0; i < 4; ++i) { el[grow0 + i] = pel[i]; er[grow0 + i] = per_[i]; }
}

// ======================= Binning (LDS-staged, coalesced writeback) ====================
// 256 threads x 16 edges = 4096 edges/block. Stage the block's edges in LDS sorted by
// bucket (hist -> single-wave scan -> LDS scatter), reserve one global run per
// (block,bucket) with one atomic, then write out LINEARLY: a wave writes 64
// consecutive staged slots (~13 runs) instead of 64 temporally-scattered 4B stores.
__global__ __launch_bounds__(256) void bin_kernel(const int* __restrict__ src,
                                                  const int* __restrict__ dst,
                                                  int* __restrict__ gcur,
                                                  int* __restrict__ pairs)
{
    __shared__ int   lp[4096];      // staged packed edges (16 KB)
    __shared__ short lb[4096];      // staged bucket ids    (8 KB)
    __shared__ int hist[NBUCK];
    __shared__ int lcur[NBUCK];     // local scatter cursor; ends at lofs+hist
    __shared__ int gbase[NBUCK];    // reserved global run base
    const int tid = threadIdx.x;
    for (int i = tid; i < NBUCK; i += 256) hist[i] = 0;
    __syncthreads();

    const int t = blockIdx.x * 256 + tid;         // 16-edge group id
    const bool act = t < N_EDGES / 16;
    int4 sv[4], dv[4];
    if (act) {
        const int4* s4 = (const int4*)src + (size_t)t * 4;
        const int4* d4 = (const int4*)dst + (size_t)t * 4;
        #pragma unroll
        for (int q = 0; q < 4; ++q) { sv[q] = s4[q]; dv[q] = d4[q]; }
        #pragma unroll
        for (int q = 0; q < 4; ++q) {
            atomicAdd(&hist[dv[q].x >> 7], 1); atomicAdd(&hist[dv[q].y >> 7], 1);
            atomicAdd(&hist[dv[q].z >> 7], 1); atomicAdd(&hist[dv[q].w >> 7], 1);
        }
    }
    __syncthreads();
    // wave 0: exclusive scan of hist -> lcur (local offsets), 13 chunks of 64
    if (tid < 64) {
        int carry = 0;
        for (int c = 0; c < (NBUCK + 63) / 64; ++c) {
            const int i = c * 64 + tid;
            const int v = (i < NBUCK) ? hist[i] : 0;
            int pre = v;
            #pragma unroll
            for (int off = 1; off < 64; off <<= 1) {
                const int n = __shfl_up(pre, off, 64);
                if (tid >= off) pre += n;
            }
            if (i < NBUCK) lcur[i] = carry + pre - v;
            carry += __shfl(pre, 63, 64);
        }
    }
    // all threads: reserve global runs
    for (int i = tid; i < NBUCK; i += 256) {
        const int hv = hist[i];
        gbase[i] = hv ? atomicAdd(&gcur[i], hv) : 0;
    }
    __syncthreads();
    // scatter into LDS staging (bucket-sorted order)
    if (act) {
        #pragma unroll
        for (int q = 0; q < 4; ++q) {
            const int ss[4] = {sv[q].x, sv[q].y, sv[q].z, sv[q].w};
            const int dd[4] = {dv[q].x, dv[q].y, dv[q].z, dv[q].w};
            #pragma unroll
            for (int r = 0; r < 4; ++r) {
                const int b = dd[r] >> 7;
                const int slot = atomicAdd(&lcur[b], 1);
                lp[slot] = (ss[r] << 7) | (dd[r] & (BW - 1));
                lb[slot] = (short)b;
            }
        }
    }
    __syncthreads();
    // linear writeback: consecutive slots -> consecutive positions within each run
    const int ecB = min(N_EDGES - blockIdx.x * 4096, 4096);
    for (int i = tid; i < ecB; i += 256) {
        const int b = lb[i];
        const int local = i - (lcur[b] - hist[b]);   // lofs[b] = lcur[b]-hist[b]
        pairs[gbase[b] + local] = lp[i];
    }
}

// ======================= Bucket-local sort (in LDS) + fused layer-1 weights ===========
// One block per bucket: stage region in LDS, hist+scan+scatter there, write sorted
// order back in place (coalesced) while computing w1 = exp(leakyrelu(el[src]+er[dst])).
__global__ __launch_bounds__(256) void lsort_kernel(
    const int* __restrict__ gcur, int* __restrict__ pairs,
    const float* __restrict__ el, const float* __restrict__ er,
    int* __restrict__ deg, int* __restrict__ rowptr, float* __restrict__ w1)
{
    __shared__ int lp[CAP];     // 16 KB
    __shared__ int lc[CAP];     // 16 KB
    __shared__ int lhist[BW];
    __shared__ int lcur[BW];
    __shared__ float ers[BW];
    __shared__ int w0tot;
    const int tid = threadIdx.x;
    const int b = blockIdx.x;
    const int rbase = b * CAP;
    const int node0 = b * BW;
    int ecnt = gcur[b] - rbase;
    if (ecnt > CAP) ecnt = CAP;                  // safety clamp (never expected)
    if (tid < BW) {
        lhist[tid] = 0;
        ers[tid] = (node0 + tid < N_NODES) ? er[node0 + tid] : 0.f;
    }
    __syncthreads();
    for (int i = tid; i < ecnt; i += 256) {
        const int p = pairs[rbase + i];
        lp[i] = p;
        atomicAdd(&lhist[p & (BW - 1)], 1);
    }
    __syncthreads();
    // exclusive scan of 128 local degrees (2 waves)
    const int lane = tid & 63;
    int v = 0;
    if (tid < BW) v = lhist[tid];
    int pre = v;
    #pragma unroll
    for (int off = 1; off < 64; off <<= 1) {
        const int n = __shfl_up(pre, off, 64);
        if (lane >= off) pre += n;
    }
    if (tid == 63) w0tot = pre;
    __syncthreads();
    if (tid < BW) {
        const int ex = pre - v + (tid >= 64 ? w0tot : 0);
        lcur[tid] = ex;
        const int node = node0 + tid;
        if (node < N_NODES) { deg[node] = v; rowptr[node] = rbase + ex; }
    }
    __syncthreads();
    for (int i = tid; i < ecnt; i += 256) {
        const int p = lp[i];
        const int slot = atomicAdd(&lcur[p & (BW - 1)], 1);
        lc[slot] = p;
    }
    __syncthreads();
    for (int i = tid; i < ecnt; i += 256) {
        const int p = lc[i];
        pairs[rbase + i] = p;
        float sc = el[p >> 7] + ers[p & (BW - 1)];
        sc = sc > 0.f ? sc : 0.2f * sc;              // LeakyReLU(0.2)
        w1[rbase + i] = __expf(sc);
    }
}

// ======================= Layer-2 weights ==============================================
// Streaming over each bucket's sorted range: w2 = exp(leakyrelu(el2[src]+er2[dst])).
__global__ __launch_bounds__(256) void wcalc_kernel(
    const int* __restrict__ gcur, const int* __restrict__ csr,
    const float* __restrict__ el, const float* __restrict__ er,
    float* __restrict__ w)
{
    __shared__ float ers[BW];
    const int tid = threadIdx.x;
    const int b = blockIdx.x;
    const int rbase = b * CAP;
    const int node0 = b * BW;
    if (tid < BW) ers[tid] = (node0 + tid < N_NODES) ? er[node0 + tid] : 0.f;
    __syncthreads();
    int ecnt = gcur[b] - rbase;
    if (ecnt > CAP) ecnt = CAP;
    for (int i = tid; i < ecnt; i += 256) {
        const int p = csr[rbase + i];
        float sc = el[p >> 7] + ers[p & (BW - 1)];
        sc = sc > 0.f ? sc : 0.2f * sc;
        w[rbase + i] = __expf(sc);
    }
}

// ======================= Gather-aggregate (r7-exact: proven 43 µs) ====================
// One node per 32-lane group; csr/w broadcast streams; h per-lane random (bf16, 64B).
// 4-deep unroll. MODE 0: out = elu(num/den + b)   MODE 1: out = num/den + b
template <int MODE>
__global__ __launch_bounds__(256) void gather_kernel(
    const int* __restrict__ rowptr, const int* __restrict__ deg,
    const int* __restrict__ csr, const float* __restrict__ w,
    const __hip_bfloat16* __restrict__ h, const float* __restrict__ bias,
    float* __restrict__ out)
{
    const int tid = threadIdx.x;
    const int node = blockIdx.x * 8 + (tid >> 5);    // grid = N/8 exactly
    const int col = tid & 31;
    const int cnt = deg[node];
    const int start = rowptr[node];
    float acc = 0.f, den = 0.f;
    int j = 0;
    for (; j + 3 < cnt; j += 4) {
        const int p0 = csr[start + j];
        const int p1 = csr[start + j + 1];
        const int p2 = csr[start + j + 2];
        const int p3 = csr[start + j + 3];
        const float w0 = w[start + j];
        const float w1v = w[start + j + 1];
        const float w2v = w[start + j + 2];
        const float w3v = w[start + j + 3];
        const float h0 = __bfloat162float(h[(size_t)(p0 >> 7) * HID + col]);
        const float h1 = __bfloat162float(h[(size_t)(p1 >> 7) * HID + col]);
        const float h2v = __bfloat162float(h[(size_t)(p2 >> 7) * HID + col]);
        const float h3 = __bfloat162float(h[(size_t)(p3 >> 7) * HID + col]);
        den += (w0 + w1v) + (w2v + w3v);
        acc += w0 * h0 + w1v * h1 + w2v * h2v + w3v * h3;
    }
    for (; j < cnt; ++j) {
        const int p = csr[start + j];
        const float wv = w[start + j];
        den += wv;
        acc += wv * __bfloat162float(h[(size_t)(p >> 7) * HID + col]);
    }
    float v = den > 0.f ? acc / den : 0.f;
    v += bias[col];
    if (MODE == 0) v = v > 0.f ? v : expm1f(v);      // ELU
    out[(size_t)node * HID + col] = v;
}

// ======================= Layer-2 GEMM (register-blocked 1x4, r7-exact) ================
// h2(bf16) = x2@W2; thread = (row, 4 cols): 2 LDS reads per 4 FMAs.
__global__ __launch_bounds__(256) void gemm2_kernel(
    const float* __restrict__ x2, const float* __restrict__ W,
    const float* __restrict__ al, const float* __restrict__ ar,
    __hip_bfloat16* __restrict__ h, float* __restrict__ el, float* __restrict__ er)
{
    __shared__ float Ws[HID][36];   // pad 36: float4-aligned rows, conflict-free
    __shared__ float Xs[32][36];
    const int tid = threadIdx.x;
    const int row0 = blockIdx.x * 32;
    {
        const float4 wv = ((const float4*)W)[tid];
        *(float4*)&Ws[tid >> 3][(tid & 7) * 4] = wv;
        const float4 xv = ((const float4*)x2)[(size_t)row0 * 8 + tid];
        *(float4*)&Xs[tid >> 3][(tid & 7) * 4] = xv;
    }
    __syncthreads();

    const int r = tid >> 3, cg = tid & 7;
    const int row = row0 + r;
    float ax = 0.f, ay = 0.f, az = 0.f, aw = 0.f;
    #pragma unroll
    for (int k = 0; k < HID; ++k) {
        const float xv = Xs[r][k];
        const float4 wv = *(const float4*)&Ws[k][cg * 4];
        ax += xv * wv.x; ay += xv * wv.y; az += xv * wv.z; aw += xv * wv.w;
    }

    ushort4 hp;
    hp.x = __builtin_bit_cast(unsigned short, __float2bfloat16(ax));
    hp.y = __builtin_bit_cast(unsigned short, __float2bfloat16(ay));
    hp.z = __builtin_bit_cast(unsigned short, __float2bfloat16(az));
    hp.w = __builtin_bit_cast(unsigned short, __float2bfloat16(aw));
    *(ushort4*)&h[(size_t)row * HID + cg * 4] = hp;

    const int c0 = cg * 4;
    float pel = ax * al[c0] + ay * al[c0 + 1] + az * al[c0 + 2] + aw * al[c0 + 3];
    float per = ax * ar[c0] + ay * ar[c0 + 1] + az * ar[c0 + 2] + aw * ar[c0 + 3];
    #pragma unroll
    for (int m = 1; m < 8; m <<= 1) {
        pel += __shfl_xor(pel, m, 8);
        per += __shfl_xor(per, m, 8);
    }
    if (cg == 0) { el[row] = pel; er[row] = per; }
}

extern "C" void kernel_launch(void* const* d_in, const int* in_sizes, int n_in,
                              void* d_out, int out_size, void* d_ws, size_t ws_size,
                              hipStream_t stream) {
    const float* features = (const float*)d_in[0];
    const int*   src      = (const int*)d_in[1];
    const int*   dst      = (const int*)d_in[2];
    const float* W1       = (const float*)d_in[3];
    const float* al1      = (const float*)d_in[4];
    const float* ar1      = (const float*)d_in[5];
    const float* b1       = (const float*)d_in[6];
    const float* W2       = (const float*)d_in[7];
    const float* al2      = (const float*)d_in[8];
    const float* ar2      = (const float*)d_in[9];
    const float* b2       = (const float*)d_in[10];
    float* out = (float*)d_out;

    // Workspace (~55 MB)
    int*  gcur   = (int*)d_ws;                          // 784
    int*  deg    = gcur + 784;                          // 100k
    int*  rowptr = deg + N_NODES;                       // 100k
    int*  pairs  = rowptr + N_NODES;                    // NBUCK*CAP (12.8 MB), sorted in place
    float* wbuf  = (float*)(pairs + NBUCK * CAP);       // NBUCK*CAP (12.8 MB)
    __hip_bfloat16* h1 = (__hip_bfloat16*)(wbuf + NBUCK * CAP);   // 6.4 MB
    float* el1 = (float*)(h1 + (size_t)N_NODES * HID);
    float* er1 = el1 + N_NODES;
    float* x2  = er1 + N_NODES;                         // 12.8 MB (f32)
    __hip_bfloat16* h2 = (__hip_bfloat16*)(x2 + (size_t)N_NODES * HID);  // 6.4 MB
    float* el2 = (float*)(h2 + (size_t)N_NODES * HID);
    float* er2 = el2 + N_NODES;

    const int NB_E16 = (N_EDGES / 16 + 255) / 256;      // 391 (16 edges/thread, 256 thr)
    const int NB_G1  = (N_NODES + 63) / 64;             // 1563

    // Layer-1 GEMM (MFMA) + cursor init
    gemm1_kernel<<<NB_G1, 256, 0, stream>>>(features, W1, al1, ar1,
                                            h1, el1, er1, gcur);
    // Edge binning (LDS-staged coalesced writeback); in-LDS bucket sort -> CSR (+ w1)
    bin_kernel<<<NB_E16, 256, 0, stream>>>(src, dst, gcur, pairs);
    lsort_kernel<<<NBUCK, 256, 0, stream>>>(gcur, pairs, el1, er1,
                                            deg, rowptr, wbuf);
    // Layer-1 aggregate -> x2 = elu(num/den + b1)
    gather_kernel<0><<<N_NODES / 8, 256, 0, stream>>>(rowptr, deg, pairs, wbuf,
                                                      h1, b1, x2);
    // Layer-2 GEMM
    gemm2_kernel<<<N_NODES / 32, 256, 0, stream>>>(x2, W2, al2, ar2, h2, el2, er2);
    // Layer-2 weights, then final aggregate -> out = num/den + b2
    wcalc_kernel<<<NBUCK, 256, 0, stream>>>(gcur, pairs, el2, er2, wbuf);
    gather_kernel<1><<<N_NODES / 8, 256, 0, stream>>>(rowptr, deg, pairs, wbuf,
                                                      h2, b2, out);
}